// Round 7
// baseline (194.783 us; speedup 1.0000x reference)
//
#include <hip/hip_runtime.h>

#define N_NODES 32768
#define E_EDGES 524288
#define HC 192          // HEADS * C_OUT
#define NEG_SLOPE 0.2f
#define BN_EPS 1e-5f

// chunked-capacity CSR: 16 chunks x cap 12 -> row stride 192
#define NCHUNK 16
#define CHK_E  32768     // E / NCHUNK
#define CAP    12        // per-(chunk,node) capacity; lambda=1 -> P(>12)~6e-11
#define PAD    (NCHUNK * CAP)   // 192
#define NRANGE 16        // node ranges of 2048
#define RNG_N  2048

#define SCT_BLOCKS (NCHUNK * NRANGE)     // 256
#define K1_BLOCKS  (SCT_BLOCKS + 512)    // + 512 a-score blocks
#define K2_BLOCKS  (N_NODES / 16)        // 2048
#define K3_BLOCKS  64
#define APPLY_BLOCKS 512
#define ZROW 200         // padded LDS z row

typedef _Float16 f16;
typedef __attribute__((ext_vector_type(8))) _Float16 v8h;   // MFMA A/B frag
typedef __attribute__((ext_vector_type(4))) float    v4f;   // MFMA C/D frag

__device__ __forceinline__ float lrelu(float v) { return v > 0.f ? v : NEG_SLOPE * v; }

__device__ __forceinline__ float wave_sum(float v) {
#pragma unroll
    for (int off = 32; off > 0; off >>= 1) v += __shfl_xor(v, off);
    return v;
}

// ---------------- K1: single-pass chunked CSR || a-scores + x16 + Wp --------
// Scatter block (c,r): LDS-hist local ranks for chunk c over node range r,
// slot = c*CAP + lr (disjoint by construction across chunks). NO device
// atomics (hard ~11 G/s floor), NO scan kernel, NO memset (cnt16 and all
// read slots are fully written here).
__global__ __launch_bounds__(256, 8) void k_build(
        const int* __restrict__ esrc, const int* __restrict__ edst,
        unsigned short* __restrict__ csr_pad,     // [N][PAD]
        unsigned short* __restrict__ cnt16,       // [N][NCHUNK]
        const float* __restrict__ x, const float* __restrict__ W,
        const float* __restrict__ att_s, const float* __restrict__ att_d,
        f16* __restrict__ x16, float* __restrict__ a_src, float* __restrict__ a_dst,
        f16* __restrict__ Wp) {
    const int bid = blockIdx.x;
    __shared__ int hist[RNG_N];                   // 8 KB
    __shared__ float us[3][64], ud[3][64];
    if (bid < SCT_BLOCKS) {
        const int c = bid >> 4, r = bid & 15;
        for (int i = threadIdx.x; i < RNG_N; i += 256) hist[i] = 0;
        __syncthreads();
        const int* __restrict__ dp = edst + c * CHK_E;
        const int* __restrict__ sp = esrc + c * CHK_E;
        for (int i = threadIdx.x; i < CHK_E; i += 256) {
            int d = dp[i];
            if ((d >> 11) == r) {
                int lr = atomicAdd(&hist[d & (RNG_N - 1)], 1);   // LDS atomic: ~free
                if (lr < CAP)
                    csr_pad[(size_t)d * PAD + c * CAP + lr] = (unsigned short)sp[i];
            }
        }
        __syncthreads();
        for (int i = threadIdx.x; i < RNG_N; i += 256) {
            int v = hist[i]; if (v > CAP) v = CAP;
            cnt16[(size_t)(r * RNG_N + i) * NCHUNK + c] = (unsigned short)v;
        }
        return;
    }
    // ---- a-score branch: a_src[n][h] = x[n] . (W-block @ att_s[h]) ---------
    const int gid = bid - SCT_BLOCKS;             // 0..511
    if (threadIdx.x < 192) {                      // u = W-block @ att (cheap, per-block)
        const int h = threadIdx.x >> 6, k = threadIdx.x & 63;
        const float* wr = W + k * HC + h * 64;
        const float* ap = att_s + h * 64;
        const float* dp = att_d + h * 64;
        float su = 0.f, du = 0.f;
#pragma unroll
        for (int ch = 0; ch < 64; ch++) {
            float w = wr[ch];
            su = fmaf(w, ap[ch], su);
            du = fmaf(w, dp[ch], du);
        }
        us[h][k] = su; ud[h][k] = du;
    }
    if (gid == 0) {
        // Wp: MFMA-order packed W' (f16): W'[c'][ch], c'=kf*32+q*8+j, ch=ct*16+nl
        for (int idx = threadIdx.x; idx < 1536; idx += 256) {
            const int kfct = idx >> 6, ln = idx & 63;
            const int kf = kfct >> 2, ct = kfct & 3;
            const int qq = ln >> 4, nn = ln & 15;
#pragma unroll
            for (int j = 0; j < 8; j++) {
                int kp = kf * 32 + qq * 8 + j;
                int h = kp >> 6, kk = kp & 63;
                Wp[(size_t)idx * 8 + j] = (f16)W[kk * HC + h * 64 + ct * 16 + nn];
            }
        }
    }
    __syncthreads();
    const int lane = threadIdx.x & 63, wv = threadIdx.x >> 6;
    const float u0 = us[0][lane], u1 = us[1][lane], u2 = us[2][lane];
    const float d0 = ud[0][lane], d1 = ud[1][lane], d2 = ud[2][lane];
    const int nbase = (gid * 4 + wv) * 16;
#pragma unroll 1
    for (int t = 0; t < 16; t++) {
        const int n = nbase + t;
        const float xv = x[n * 64 + lane];        // flat rows == reshape(-1,64)
        x16[n * 64 + lane] = (f16)xv;
        float s0 = wave_sum(xv * u0), s1 = wave_sum(xv * u1), s2 = wave_sum(xv * u2);
        float t0 = wave_sum(xv * d0), t1 = wave_sum(xv * d1), t2 = wave_sum(xv * d2);
        if (lane == 0) {
            ((float4*)a_src)[n] = make_float4(s0, s1, s2, 0.f);
            ((float4*)a_dst)[n] = make_float4(t0, t1, t2, 0.f);
        }
    }
}

// ---------------- K2: aggregation -> LDS z -> MFMA GEMM + BN partials -------
// Segment-prefix walk maps lane j -> j-th neighbor across the 16 chunk
// segments (counts wave-uniform). BN partials: NON-atomic per-block stores
// (R5/R6 issued 262K device atomics here ~= the scatter's entire budget).
__global__ __launch_bounds__(256, 8) void k_agg(
        const f16* __restrict__ x16,
        const float* __restrict__ a_src,  // [N][4]
        const float* __restrict__ a_dst,  // [N][4]
        const unsigned short* __restrict__ cnt16,
        const unsigned short* __restrict__ csr_pad,
        const f16* __restrict__ Wp,
        const float* __restrict__ bias,
        float* __restrict__ out_pre,
        float* __restrict__ gps1, float* __restrict__ gps2) {  // [K2_BLOCKS][64]
    const int lane = threadIdx.x & 63;
    const int wv = threadIdx.x >> 6;
    const int bid = blockIdx.x;
    const int n0 = bid * 16;

    __shared__ f16 zlds[16][ZROW];
    __shared__ float4 wsl[4][64];     // wave-private: no barrier needed

#pragma unroll 1
    for (int r = 0; r < 4; r++) {
        const int n = n0 + (r << 2) + wv;
        // ---- segment walk: lane j holds the j-th neighbor ------------------
        const unsigned int* __restrict__ cp =
            (const unsigned int*)(cnt16 + (size_t)n * NCHUNK);   // 8 uints
        int pfx = 0, myslot = 0;
#pragma unroll
        for (int u = 0; u < 8; u++) {
            unsigned int w = cp[u];
            int c0 = (int)(w & 0xffffu), c1 = (int)(w >> 16);
            if (lane >= pfx && lane < pfx + c0) myslot = (2 * u) * CAP + (lane - pfx);
            pfx += c0;
            if (lane >= pfx && lane < pfx + c1) myslot = (2 * u + 1) * CAP + (lane - pfx);
            pfx += c1;
        }
        int deg = pfx > 64 ? 64 : pfx;
        const float ad0 = a_dst[n * 4 + 0], ad1 = a_dst[n * 4 + 1], ad2 = a_dst[n * 4 + 2];
        float ws0 = __expf(lrelu(a_src[n * 4 + 0] + ad0));
        float ws1 = __expf(lrelu(a_src[n * 4 + 1] + ad1));
        float ws2 = __expf(lrelu(a_src[n * 4 + 2] + ad2));
        int s = 0;
        float w0 = 0.f, w1 = 0.f, w2 = 0.f;
        if (lane < deg) {
            s = (int)csr_pad[(size_t)n * PAD + myslot];
            float4 as = ((const float4*)a_src)[s];   // L2-resident (512 KB)
            w0 = __expf(lrelu(as.x + ad0));
            w1 = __expf(lrelu(as.y + ad1));
            w2 = __expf(lrelu(as.z + ad2));
        }
        float den0 = ws0 + wave_sum(w0);
        float den1 = ws1 + wave_sum(w1);
        float den2 = ws2 + wave_sum(w2);
        const float i0 = 1.f / (3.f * den0);         // fold head-mean 1/3
        const float i1 = 1.f / (3.f * den1);
        const float i2 = 1.f / (3.f * den2);
        wsl[wv][lane] = make_float4(w0 * i0, w1 * i1, w2 * i2, 0.f);
        const float xs = (float)x16[(size_t)n * 64 + lane];
        float z0 = ws0 * i0 * xs, z1 = ws1 * i1 * xs, z2 = ws2 * i2 * xs;
        int j = 0;
        for (; j + 8 <= deg; j += 8) {
            int sj[8]; float xv[8];
#pragma unroll
            for (int u = 0; u < 8; u++) sj[u] = __builtin_amdgcn_readlane(s, j + u);
#pragma unroll
            for (int u = 0; u < 8; u++) xv[u] = (float)x16[(size_t)sj[u] * 64 + lane];
#pragma unroll
            for (int u = 0; u < 8; u++) {
                float4 wj = wsl[wv][j + u];
                z0 = fmaf(wj.x, xv[u], z0);
                z1 = fmaf(wj.y, xv[u], z1);
                z2 = fmaf(wj.z, xv[u], z2);
            }
        }
        for (; j < deg; j++) {
            int sa = __builtin_amdgcn_readlane(s, j);
            float xa = (float)x16[(size_t)sa * 64 + lane];
            float4 wj = wsl[wv][j];
            z0 = fmaf(wj.x, xa, z0);
            z1 = fmaf(wj.y, xa, z1);
            z2 = fmaf(wj.z, xa, z2);
        }
        const int rl = (r << 2) + wv;                // node-local row
        zlds[rl][lane]       = (f16)z0;
        zlds[rl][64 + lane]  = (f16)z1;
        zlds[rl][128 + lane] = (f16)z2;
    }
    __syncthreads();

    // MFMA: wave wv computes channels [wv*16, wv*16+16) x 16 nodes
    const int q = lane >> 4, nl = lane & 15;
    v4f C = {0.f, 0.f, 0.f, 0.f};
#pragma unroll
    for (int kf = 0; kf < 6; kf++) {
        v8h zb = *(const v8h*)(&zlds[nl][kf * 32 + q * 8]);
        v8h wa = *(const v8h*)(Wp + ((size_t)(kf * 4 + wv) * 64 + lane) * 8);
        C = __builtin_amdgcn_mfma_f32_16x16x32_f16(wa, zb, C, 0, 0, 0);
    }
    const int ch0 = wv * 16 + q * 4;
    float4 bv = *(const float4*)(bias + ch0);
    float o0 = C[0] + bv.x, o1 = C[1] + bv.y, o2 = C[2] + bv.z, o3 = C[3] + bv.w;
    *(float4*)(out_pre + (size_t)(n0 + nl) * 64 + ch0) = make_float4(o0, o1, o2, o3);
    // BN partials over the 16 node-columns; plain stores into private row
    float r0 = o0, r1 = o1, r2 = o2, r3 = o3;
    float q0 = o0 * o0, q1 = o1 * o1, q2 = o2 * o2, q3 = o3 * o3;
#pragma unroll
    for (int off = 1; off < 16; off <<= 1) {
        r0 += __shfl_xor(r0, off); r1 += __shfl_xor(r1, off);
        r2 += __shfl_xor(r2, off); r3 += __shfl_xor(r3, off);
        q0 += __shfl_xor(q0, off); q1 += __shfl_xor(q1, off);
        q2 += __shfl_xor(q2, off); q3 += __shfl_xor(q3, off);
    }
    if (nl == 0) {
        float* g1 = gps1 + (size_t)bid * 64 + ch0;
        float* g2 = gps2 + (size_t)bid * 64 + ch0;
        g1[0] = r0; g1[1] = r1; g1[2] = r2; g1[3] = r3;
        g2[0] = q0; g2[1] = q1; g2[2] = q2; g2[3] = q3;
    }
}

// ---------------- K3: reduce per-block BN partials 2048 -> 64 rows ----------
__global__ __launch_bounds__(256) void k_red(const float* __restrict__ gps1,
                                             const float* __restrict__ gps2,
                                             float* __restrict__ gp1,
                                             float* __restrict__ gp2) {
    const int b = blockIdx.x;                 // 0..63, owns rows [b*32, b*32+32)
    const int ch = threadIdx.x & 63, g = threadIdx.x >> 6;
    __shared__ float r1[4][64], r2[4][64];
    float s1 = 0.f, s2 = 0.f;
#pragma unroll
    for (int rr = 0; rr < 8; rr++) {
        int row = b * 32 + g * 8 + rr;
        s1 += gps1[row * 64 + ch];
        s2 += gps2[row * 64 + ch];
    }
    r1[g][ch] = s1; r2[g][ch] = s2;
    __syncthreads();
    if (threadIdx.x < 64) {
        gp1[b * 64 + threadIdx.x] = r1[0][threadIdx.x] + r1[1][threadIdx.x]
                                  + r1[2][threadIdx.x] + r1[3][threadIdx.x];
        gp2[b * 64 + threadIdx.x] = r2[0][threadIdx.x] + r2[1][threadIdx.x]
                                  + r2[2][threadIdx.x] + r2[3][threadIdx.x];
    }
}

// ---------------- K4: BN finalize (parallel over 256 thr) + apply -----------
__global__ __launch_bounds__(256) void k_apply(const float4* __restrict__ out_pre4,
                                               const float* __restrict__ gp1,
                                               const float* __restrict__ gp2,
                                               const float* __restrict__ gamma,
                                               const float* __restrict__ beta,
                                               float4* __restrict__ out4) {
    __shared__ float sc[64], sh[64];
    __shared__ float rs[256], rq[256];
    {
        const int t = threadIdx.x & 63, g = threadIdx.x >> 6;
        float s = 0.f, q = 0.f;
#pragma unroll
        for (int i = 0; i < 16; i++) {
            s += gp1[(g * 16 + i) * 64 + t];
            q += gp2[(g * 16 + i) * 64 + t];
        }
        rs[threadIdx.x] = s;
        rq[threadIdx.x] = q;
    }
    __syncthreads();
    if (threadIdx.x < 64) {
        int t = threadIdx.x;
        float s = rs[t] + rs[64 + t] + rs[128 + t] + rs[192 + t];
        float q = rq[t] + rq[64 + t] + rq[128 + t] + rq[192 + t];
        const float inv_n = 1.0f / (float)N_NODES;
        float mu = s * inv_n;
        float var = q * inv_n - mu * mu;
        float invstd = 1.0f / sqrtf(var + BN_EPS);
        float scale = invstd * gamma[t];
        sc[t] = scale;
        sh[t] = beta[t] - mu * scale;
    }
    __syncthreads();
    const int total = N_NODES * 64 / 4;
    for (int idx = blockIdx.x * 256 + threadIdx.x; idx < total; idx += APPLY_BLOCKS * 256) {
        int c0 = (idx * 4) & 63;
        float4 v = out_pre4[idx];
        float4 r;
        r.x = fmaxf(v.x * sc[c0 + 0] + sh[c0 + 0], 0.f);
        r.y = fmaxf(v.y * sc[c0 + 1] + sh[c0 + 1], 0.f);
        r.z = fmaxf(v.z * sc[c0 + 2] + sh[c0 + 2], 0.f);
        r.w = fmaxf(v.w * sc[c0 + 3] + sh[c0 + 3], 0.f);
        out4[idx] = r;
    }
}

// ---------------- host launcher ----------------------------------------------
extern "C" void kernel_launch(void* const* d_in, const int* in_sizes, int n_in,
                              void* d_out, int out_size, void* d_ws, size_t ws_size,
                              hipStream_t stream) {
    const float* x     = (const float*)d_in[0];
    const int*   ei    = (const int*)d_in[2];     // [2, E]: row0 src, row1 dst
    const float* W     = (const float*)d_in[3];
    const float* att_s = (const float*)d_in[4];
    const float* att_d = (const float*)d_in[5];
    const float* bias  = (const float*)d_in[6];
    const float* gamma = (const float*)d_in[9];
    const float* beta  = (const float*)d_in[10];
    float* out = (float*)d_out;

    char* ws = (char*)d_ws;
    size_t off = 0;
    auto alloc = [&](size_t bytes) -> void* {
        void* p = ws + off;
        off += (bytes + 255) & ~(size_t)255;
        return p;
    };
    unsigned short* csr_pad = (unsigned short*)alloc((size_t)N_NODES * PAD * 2); // 12.6 MB
    unsigned short* cnt16   = (unsigned short*)alloc((size_t)N_NODES * NCHUNK * 2); // 1 MB
    f16*            x16     = (f16*)alloc((size_t)N_NODES * 64 * 2);       // 4 MB
    float*          a_src   = (float*)alloc((size_t)N_NODES * 4 * 4);      // 512 KB
    float*          a_dst   = (float*)alloc((size_t)N_NODES * 4 * 4);
    f16*            Wp      = (f16*)alloc((size_t)1536 * 8 * 2);           // 24 KB
    float*          gps1    = (float*)alloc((size_t)K2_BLOCKS * 64 * 4);   // 512 KB
    float*          gps2    = (float*)alloc((size_t)K2_BLOCKS * 64 * 4);
    float*          gp1     = (float*)alloc(64 * 64 * 4);                  // 16 KB
    float*          gp2     = (float*)alloc(64 * 64 * 4);
    float*          out_pre = (float*)alloc((size_t)N_NODES * 64 * 4);     // 8 MB

    const int* esrc = ei;
    const int* edst = ei + E_EDGES;

    k_build<<<K1_BLOCKS, 256, 0, stream>>>(
        esrc, edst, csr_pad, cnt16, x, W, att_s, att_d, x16, a_src, a_dst, Wp);
    k_agg<<<K2_BLOCKS, 256, 0, stream>>>(x16, a_src, a_dst, cnt16, csr_pad, Wp,
                                         bias, out_pre, gps1, gps2);
    k_red<<<K3_BLOCKS, 256, 0, stream>>>(gps1, gps2, gp1, gp2);
    k_apply<<<APPLY_BLOCKS, 256, 0, stream>>>((const float4*)out_pre, gp1, gp2,
                                              gamma, beta, (float4*)out);
}

// Round 8
// 150.117 us; speedup vs baseline: 1.2975x; 1.2975x over previous
//
#include <hip/hip_runtime.h>
#include <hip/hip_bf16.h>

#define N_NODES 32768
#define E_EDGES 524288
#define HC 192          // HEADS * C_OUT
#define NEG_SLOPE 0.2f
#define BN_EPS 1e-5f
#define PAD 64          // padded-CSR row stride (deg ~ Binom mean 16, sd 4; P(>64)~1e-33)

typedef _Float16 f16;
typedef __attribute__((ext_vector_type(8))) _Float16 v8h;   // MFMA A/B frag (4 VGPRs)
typedef __attribute__((ext_vector_type(4))) float    v4f;   // MFMA C/D frag

#define SCAT_BLOCKS 256                 // 8 edges/thread: 8 atomics in flight
#define GEMM_BLOCKS 512                 // 2048 waves; 1 row-tile (16 nodes) per wave
#define FUSED_BLOCKS (SCAT_BLOCKS + GEMM_BLOCKS)   // 768 <= 1024 resident @4/CU

#define NODE_BLOCKS 8192                // 1 node/wave: max TLP for gather latency
#define APPLY_BLOCKS 512

__device__ __forceinline__ float lrelu(float v) { return v > 0.f ? v : NEG_SLOPE * v; }

__device__ __forceinline__ float wave_sum(float v) {
#pragma unroll
    for (int off = 32; off > 0; off >>= 1) v += __shfl_xor(v, off);
    return v;
}
__device__ __forceinline__ float rlane(float v, int l) {
    return __uint_as_float(__builtin_amdgcn_readlane(__float_as_uint(v), l));
}

// ---------------- K1 (fused): CSR scatter || MFMA h-gemm --------------------
// Blocks 0..255: scatter, 8 edges/thread -- 8 independent atomicAdds issued
// back-to-back (R1->R2 showed 1->4-deep helped; the device RMW unit is the
// measured ~11 G/s floor, so fill its pipe). Blocks 256..767: h-GEMM.
// 768 blocks = fully resident in one round @4/CU -> true overlap, no tail.
__global__ __launch_bounds__(256, 4) void k_fused(
        const int* __restrict__ esrc, const int* __restrict__ edst,
        int* __restrict__ cnt, unsigned short* __restrict__ csr_pad,
        const float* __restrict__ x, const float* __restrict__ W,
        const float* __restrict__ att_s, const float* __restrict__ att_d,
        f16* __restrict__ hh, float* __restrict__ a_src, float* __restrict__ a_dst,
        float* __restrict__ gp1, float* __restrict__ gp2) {
    const int bid = blockIdx.x;
    if (bid < SCAT_BLOCKS) {
        // ---- scatter branch: 8 edges/thread, 8 atomics in flight ---------
        const int base = bid * 2048 + threadIdx.x;
        int s[8], d[8], p[8];
#pragma unroll
        for (int u = 0; u < 8; u++) {
            s[u] = esrc[base + u * 256];
            d[u] = edst[base + u * 256];
        }
#pragma unroll
        for (int u = 0; u < 8; u++) p[u] = atomicAdd(&cnt[d[u]], 1);
#pragma unroll
        for (int u = 0; u < 8; u++)
            if (p[u] < PAD) csr_pad[d[u] * PAD + p[u]] = (unsigned short)s[u];
        return;
    }
    // ---- MFMA gemm branch ------------------------------------------------
    const int gid = bid - SCAT_BLOCKS;  // 0..511
    if (gid == 0) {                     // zero BN partials (4096 floats each)
        float4 z = make_float4(0.f, 0.f, 0.f, 0.f);
#pragma unroll
        for (int i2 = 0; i2 < 4; i2++) {
            ((float4*)gp1)[threadIdx.x * 4 + i2] = z;
            ((float4*)gp2)[threadIdx.x * 4 + i2] = z;
        }
    }
    const int lane = threadIdx.x & 63;
    const int wid  = (gid * 256 + threadIdx.x) >> 6;          // 0..2047
    const int q    = lane >> 4;          // quad 0..3
    const int nl   = lane & 15;
    const int n0   = wid * 16;           // 16-node row-tile

    // B frags: x^T -- lane holds x[n0+nl][kf*32 + q*8 + j], j=0..7
    v8h xf0, xf1;
    {
        const float* xr = x + (size_t)(n0 + nl) * 64 + q * 8;
        float4 lo = *(const float4*)(xr);
        float4 hi = *(const float4*)(xr + 4);
        xf0[0] = (f16)lo.x; xf0[1] = (f16)lo.y; xf0[2] = (f16)lo.z; xf0[3] = (f16)lo.w;
        xf0[4] = (f16)hi.x; xf0[5] = (f16)hi.y; xf0[6] = (f16)hi.z; xf0[7] = (f16)hi.w;
        lo = *(const float4*)(xr + 32);
        hi = *(const float4*)(xr + 36);
        xf1[0] = (f16)lo.x; xf1[1] = (f16)lo.y; xf1[2] = (f16)lo.z; xf1[3] = (f16)lo.w;
        xf1[4] = (f16)hi.x; xf1[5] = (f16)hi.y; xf1[6] = (f16)hi.z; xf1[7] = (f16)hi.w;
    }

    float sAcc = 0.f, dAcc = 0.f;
#pragma unroll
    for (int ct = 0; ct < 12; ct++) {
        const int c = ct * 16 + nl;
        // A frags: W^T -- lane holds W[kf*32 + q*8 + j][ct*16 + nl]
        v8h wf0, wf1;
#pragma unroll
        for (int j = 0; j < 8; j++) {
            wf0[j] = (f16)W[(q * 8 + j) * HC + c];
            wf1[j] = (f16)W[(32 + q * 8 + j) * HC + c];
        }
        float4 av = *(const float4*)(att_s + ct * 16 + q * 4);
        float4 dv = *(const float4*)(att_d + ct * 16 + q * 4);

        v4f C = {0.f, 0.f, 0.f, 0.f};
        C = __builtin_amdgcn_mfma_f32_16x16x32_f16(wf0, xf0, C, 0, 0, 0);
        C = __builtin_amdgcn_mfma_f32_16x16x32_f16(wf1, xf1, C, 0, 0, 0);

        // h store: node = n0+nl, c = ct*16 + q*4 + {0..3} -> packed 8B
        union { f16 h[4]; unsigned long long u; } pk;
        pk.h[0] = (f16)C[0]; pk.h[1] = (f16)C[1];
        pk.h[2] = (f16)C[2]; pk.h[3] = (f16)C[3];
        *(unsigned long long*)(hh + (size_t)(n0 + nl) * HC + ct * 16 + q * 4) = pk.u;

        // att-score partials (av aligns exactly with C[0..3])
        sAcc = fmaf(C[0], av.x, sAcc); sAcc = fmaf(C[1], av.y, sAcc);
        sAcc = fmaf(C[2], av.z, sAcc); sAcc = fmaf(C[3], av.w, sAcc);
        dAcc = fmaf(C[0], dv.x, dAcc); dAcc = fmaf(C[1], dv.y, dAcc);
        dAcc = fmaf(C[2], dv.z, dAcc); dAcc = fmaf(C[3], dv.w, dAcc);

        if ((ct & 3) == 3) {            // head boundary: reduce over quads
            float s = sAcc; s += __shfl_xor(s, 16); s += __shfl_xor(s, 32);
            float d = dAcc; d += __shfl_xor(d, 16); d += __shfl_xor(d, 32);
            if (lane < 16) {
                a_src[(n0 + lane) * 4 + (ct >> 2)] = s;
                a_dst[(n0 + lane) * 4 + (ct >> 2)] = d;
            }
            sAcc = 0.f; dAcc = 0.f;
        }
    }
}

// ---------------- K2: single-pass GAT aggregation (one wave per node) -------
// 1 node/wave, 8192 blocks, 8 blocks/CU. Inner loop restructured to issue all
// 24 gather loads of an 8-neighbor batch BEFORE any FMA (MLP 12 -> 24
// outstanding; src idx + weights are readlane->SGPR, loads are SGPR-base +
// shared lane offset, so VGPR cost ~ 24 destinations -> stays under 64).
__global__ __launch_bounds__(256, 8) void k_node(
        const f16* __restrict__ hh,
        const float* __restrict__ a_src,  // [N][4]
        const float* __restrict__ a_dst,  // [N][4]
        const int* __restrict__ cnt,
        const unsigned short* __restrict__ csr_pad,
        const float* __restrict__ bias,
        float* __restrict__ out_pre,
        float* __restrict__ gp1,
        float* __restrict__ gp2) {
    const int lane = threadIdx.x & 63;
    const int wv = threadIdx.x >> 6;
    const int n = blockIdx.x * 4 + wv;

    int deg = cnt[n]; if (deg > PAD) deg = PAD;
    const unsigned short* __restrict__ row = csr_pad + n * PAD;

    const float ad0 = a_dst[n * 4 + 0], ad1 = a_dst[n * 4 + 1], ad2 = a_dst[n * 4 + 2];

    // self loop
    float ws0 = __expf(lrelu(a_src[n * 4 + 0] + ad0));
    float ws1 = __expf(lrelu(a_src[n * 4 + 1] + ad1));
    float ws2 = __expf(lrelu(a_src[n * 4 + 2] + ad2));
    float den0 = ws0, den1 = ws1, den2 = ws2;
    const f16* hn = hh + (size_t)n * HC;
    float acc0 = ws0 * (float)hn[lane];
    float acc1 = ws1 * (float)hn[64 + lane];
    float acc2 = ws2 * (float)hn[128 + lane];

    // deg <= PAD = 64 -> single chunk
    int s = 0;
    float w0 = 0.f, w1 = 0.f, w2 = 0.f;
    if (lane < deg) {
        s = (int)row[lane];
        float4 as = ((const float4*)a_src)[s];   // L2-resident (512 KB)
        w0 = __expf(lrelu(as.x + ad0));
        w1 = __expf(lrelu(as.y + ad1));
        w2 = __expf(lrelu(as.z + ad2));
    }
    den0 += wave_sum(w0);
    den1 += wave_sum(w1);
    den2 += wave_sum(w2);

    int j = 0;
    for (; j + 8 <= deg; j += 8) {
        // all 8 src indices (SGPRs) and 24 load issues up front
        int s_[8];
#pragma unroll
        for (int u = 0; u < 8; u++) s_[u] = __builtin_amdgcn_readlane(s, j + u);
        float v0[8], v1[8], v2[8];
#pragma unroll
        for (int u = 0; u < 8; u++) {
            const f16* __restrict__ hp = hh + (size_t)s_[u] * HC;
            v0[u] = (float)hp[lane];
            v1[u] = (float)hp[64 + lane];
            v2[u] = (float)hp[128 + lane];
        }
#pragma unroll
        for (int u = 0; u < 8; u++) {
            float wa0 = rlane(w0, j + u), wa1 = rlane(w1, j + u), wa2 = rlane(w2, j + u);
            acc0 = fmaf(wa0, v0[u], acc0);
            acc1 = fmaf(wa1, v1[u], acc1);
            acc2 = fmaf(wa2, v2[u], acc2);
        }
    }
    for (; j < deg; j++) {
        int sa = __builtin_amdgcn_readlane(s, j);
        const f16* __restrict__ ha = hh + (size_t)sa * HC;
        float wa0 = rlane(w0, j), wa1 = rlane(w1, j), wa2 = rlane(w2, j);
        acc0 = fmaf(wa0, (float)ha[lane], acc0);
        acc1 = fmaf(wa1, (float)ha[64 + lane], acc1);
        acc2 = fmaf(wa2, (float)ha[128 + lane], acc2);
    }

    float outv = (acc0 / den0 + acc1 / den1 + acc2 / den2) * (1.0f / 3.0f) + bias[lane];
    out_pre[n * 64 + lane] = outv;

    // fused BN partial stats
    __shared__ float ls[4][64], lq[4][64];
    ls[wv][lane] = outv;
    lq[wv][lane] = outv * outv;
    __syncthreads();
    if (threadIdx.x < 64) {
        int t = threadIdx.x;
        float s_ = ls[0][t] + ls[1][t] + ls[2][t] + ls[3][t];
        float q_ = lq[0][t] + lq[1][t] + lq[2][t] + lq[3][t];
        int slice = blockIdx.x & 63;
        atomicAdd(&gp1[slice * 64 + t], s_);
        atomicAdd(&gp2[slice * 64 + t], q_);
    }
}

// ---------------- K3: BN finalize (parallel over 256 thr) + apply -----------
__global__ __launch_bounds__(256) void k_apply(const float4* __restrict__ out_pre4,
                                               const float* __restrict__ gp1,
                                               const float* __restrict__ gp2,
                                               const float* __restrict__ gamma,
                                               const float* __restrict__ beta,
                                               float4* __restrict__ out4) {
    __shared__ float sc[64], sh[64];
    __shared__ float rs[256], rq[256];
    {
        const int t = threadIdx.x & 63, g = threadIdx.x >> 6;
        float s = 0.f, q = 0.f;
#pragma unroll
        for (int i = 0; i < 16; i++) {
            s += gp1[(g * 16 + i) * 64 + t];
            q += gp2[(g * 16 + i) * 64 + t];
        }
        rs[threadIdx.x] = s;
        rq[threadIdx.x] = q;
    }
    __syncthreads();
    if (threadIdx.x < 64) {
        int t = threadIdx.x;
        float s = rs[t] + rs[64 + t] + rs[128 + t] + rs[192 + t];
        float q = rq[t] + rq[64 + t] + rq[128 + t] + rq[192 + t];
        const float inv_n = 1.0f / (float)N_NODES;
        float mu = s * inv_n;
        float var = q * inv_n - mu * mu;
        float invstd = 1.0f / sqrtf(var + BN_EPS);
        float scale = invstd * gamma[t];
        sc[t] = scale;
        sh[t] = beta[t] - mu * scale;
    }
    __syncthreads();
    const int total = N_NODES * 64 / 4;
    for (int idx = blockIdx.x * 256 + threadIdx.x; idx < total; idx += APPLY_BLOCKS * 256) {
        int c0 = (idx * 4) & 63;
        float4 v = out_pre4[idx];
        float4 r;
        r.x = fmaxf(v.x * sc[c0 + 0] + sh[c0 + 0], 0.f);
        r.y = fmaxf(v.y * sc[c0 + 1] + sh[c0 + 1], 0.f);
        r.z = fmaxf(v.z * sc[c0 + 2] + sh[c0 + 2], 0.f);
        r.w = fmaxf(v.w * sc[c0 + 3] + sh[c0 + 3], 0.f);
        out4[idx] = r;
    }
}

// ---------------- host launcher ----------------------------------------------
extern "C" void kernel_launch(void* const* d_in, const int* in_sizes, int n_in,
                              void* d_out, int out_size, void* d_ws, size_t ws_size,
                              hipStream_t stream) {
    const float* x     = (const float*)d_in[0];
    const int*   ei    = (const int*)d_in[2];     // [2, E]: row0 src, row1 dst
    const float* W     = (const float*)d_in[3];
    const float* att_s = (const float*)d_in[4];
    const float* att_d = (const float*)d_in[5];
    const float* bias  = (const float*)d_in[6];
    const float* gamma = (const float*)d_in[9];
    const float* beta  = (const float*)d_in[10];
    float* out = (float*)d_out;

    char* ws = (char*)d_ws;
    size_t off = 0;
    auto alloc = [&](size_t bytes) -> void* {
        void* p = ws + off;
        off += (bytes + 255) & ~(size_t)255;
        return p;
    };
    f16*            hh      = (f16*)alloc((size_t)N_NODES * HC * 2);       // 12.6 MB
    float*          a_src   = (float*)alloc((size_t)N_NODES * 4 * 4);      // 512 KB
    float*          a_dst   = (float*)alloc((size_t)N_NODES * 4 * 4);
    int*            cnt     = (int*)alloc((size_t)N_NODES * 4);            // 128 KB
    unsigned short* csr_pad = (unsigned short*)alloc((size_t)N_NODES * PAD * 2); // 4 MB
    float*          out_pre = (float*)alloc((size_t)N_NODES * 64 * 4);     // 8.4 MB
    float*          gp1     = (float*)alloc(64 * 64 * 4);
    float*          gp2     = (float*)alloc(64 * 64 * 4);

    hipMemsetAsync(cnt, 0, (size_t)N_NODES * 4, stream);

    k_fused<<<FUSED_BLOCKS, 256, 0, stream>>>(
        ei, ei + E_EDGES, cnt, csr_pad,
        x, W, att_s, att_d, hh, a_src, a_dst, gp1, gp2);
    k_node<<<NODE_BLOCKS, 256, 0, stream>>>(hh, a_src, a_dst, cnt, csr_pad, bias,
                                            out_pre, gp1, gp2);
    k_apply<<<APPLY_BLOCKS, 256, 0, stream>>>((const float4*)out_pre, gp1, gp2,
                                              gamma, beta, (float4*)out);
}

// Round 9
// 141.511 us; speedup vs baseline: 1.3764x; 1.0608x over previous
//
#include <hip/hip_runtime.h>
#include <hip/hip_bf16.h>

#define N_NODES 32768
#define E_EDGES 524288
#define HC 192          // HEADS * C_OUT
#define NEG_SLOPE 0.2f
#define BN_EPS 1e-5f
#define PAD 64          // padded-CSR row stride (deg ~ Binom mean 16, sd 4; P(>64)~1e-33)

typedef _Float16 f16;
typedef __attribute__((ext_vector_type(8))) _Float16 v8h;   // MFMA A/B frag (4 VGPRs)
typedef __attribute__((ext_vector_type(4))) float    v4f;   // MFMA C/D frag

#define GEMM_BLOCKS 512                 // 2048 waves; 1 row-tile (16 nodes) per wave
#define SCAT_BLOCKS 512                 // 4 edges/thread, 4 outstanding atomics
#define FUSED_BLOCKS (GEMM_BLOCKS + SCAT_BLOCKS)   // 1024 = fully resident @4/CU

#define NODE_BLOCKS 8192                // 1 node/wave: max TLP for gather latency
#define APPLY_BLOCKS 512

__device__ __forceinline__ float lrelu(float v) { return v > 0.f ? v : NEG_SLOPE * v; }

__device__ __forceinline__ float wave_sum(float v) {
#pragma unroll
    for (int off = 32; off > 0; off >>= 1) v += __shfl_xor(v, off);
    return v;
}
__device__ __forceinline__ float rlane(float v, int l) {
    return __uint_as_float(__builtin_amdgcn_readlane(__float_as_uint(v), l));
}

// ---------------- K1 (fused): MFMA gemm || CSR scatter ----------------------
// R2 config restored verbatim (empirical best across 9 tested structures):
// even blocks gemm, odd blocks scatter with 4 edges/thread, 4 atomics in
// flight, 1024 blocks = one residency round @4/CU.
__global__ __launch_bounds__(256, 4) void k_fused(
        const int* __restrict__ esrc, const int* __restrict__ edst,
        int* __restrict__ cnt, unsigned short* __restrict__ csr_pad,
        const float* __restrict__ x, const float* __restrict__ W,
        const float* __restrict__ att_s, const float* __restrict__ att_d,
        f16* __restrict__ hh, float* __restrict__ a_src, float* __restrict__ a_dst,
        float* __restrict__ gp1, float* __restrict__ gp2) {
    const int bid = blockIdx.x;
    if (bid & 1) {
        // ---- scatter branch: 4 edges/thread ------------------------------
        const int base = (bid >> 1) * 1024 + threadIdx.x;
        int s0 = esrc[base];       int d0 = edst[base];
        int s1 = esrc[base + 256]; int d1 = edst[base + 256];
        int s2 = esrc[base + 512]; int d2 = edst[base + 512];
        int s3 = esrc[base + 768]; int d3 = edst[base + 768];
        int p0 = atomicAdd(&cnt[d0], 1);
        int p1 = atomicAdd(&cnt[d1], 1);
        int p2 = atomicAdd(&cnt[d2], 1);
        int p3 = atomicAdd(&cnt[d3], 1);
        if (p0 < PAD) csr_pad[d0 * PAD + p0] = (unsigned short)s0;
        if (p1 < PAD) csr_pad[d1 * PAD + p1] = (unsigned short)s1;
        if (p2 < PAD) csr_pad[d2 * PAD + p2] = (unsigned short)s2;
        if (p3 < PAD) csr_pad[d3 * PAD + p3] = (unsigned short)s3;
        return;
    }
    // ---- MFMA gemm branch ------------------------------------------------
    const int gid = bid >> 1;           // 0..511
    if (gid == 0) {                     // zero BN partials (4096 floats each)
        float4 z = make_float4(0.f, 0.f, 0.f, 0.f);
#pragma unroll
        for (int i2 = 0; i2 < 4; i2++) {
            ((float4*)gp1)[threadIdx.x * 4 + i2] = z;
            ((float4*)gp2)[threadIdx.x * 4 + i2] = z;
        }
    }
    const int lane = threadIdx.x & 63;
    const int wid  = (gid * 256 + threadIdx.x) >> 6;          // 0..2047
    const int q    = lane >> 4;          // quad 0..3
    const int nl   = lane & 15;
    const int n0   = wid * 16;           // 16-node row-tile

    // B frags: x^T -- lane holds x[n0+nl][kf*32 + q*8 + j], j=0..7
    v8h xf0, xf1;
    {
        const float* xr = x + (size_t)(n0 + nl) * 64 + q * 8;
        float4 lo = *(const float4*)(xr);
        float4 hi = *(const float4*)(xr + 4);
        xf0[0] = (f16)lo.x; xf0[1] = (f16)lo.y; xf0[2] = (f16)lo.z; xf0[3] = (f16)lo.w;
        xf0[4] = (f16)hi.x; xf0[5] = (f16)hi.y; xf0[6] = (f16)hi.z; xf0[7] = (f16)hi.w;
        lo = *(const float4*)(xr + 32);
        hi = *(const float4*)(xr + 36);
        xf1[0] = (f16)lo.x; xf1[1] = (f16)lo.y; xf1[2] = (f16)lo.z; xf1[3] = (f16)lo.w;
        xf1[4] = (f16)hi.x; xf1[5] = (f16)hi.y; xf1[6] = (f16)hi.z; xf1[7] = (f16)hi.w;
    }

    float sAcc = 0.f, dAcc = 0.f;
#pragma unroll
    for (int ct = 0; ct < 12; ct++) {
        const int c = ct * 16 + nl;
        // A frags: W^T -- lane holds W[kf*32 + q*8 + j][ct*16 + nl]
        v8h wf0, wf1;
#pragma unroll
        for (int j = 0; j < 8; j++) {
            wf0[j] = (f16)W[(q * 8 + j) * HC + c];
            wf1[j] = (f16)W[(32 + q * 8 + j) * HC + c];
        }
        float4 av = *(const float4*)(att_s + ct * 16 + q * 4);
        float4 dv = *(const float4*)(att_d + ct * 16 + q * 4);

        v4f C = {0.f, 0.f, 0.f, 0.f};
        C = __builtin_amdgcn_mfma_f32_16x16x32_f16(wf0, xf0, C, 0, 0, 0);
        C = __builtin_amdgcn_mfma_f32_16x16x32_f16(wf1, xf1, C, 0, 0, 0);

        // h store: node = n0+nl, c = ct*16 + q*4 + {0..3} -> packed 8B
        union { f16 h[4]; unsigned long long u; } pk;
        pk.h[0] = (f16)C[0]; pk.h[1] = (f16)C[1];
        pk.h[2] = (f16)C[2]; pk.h[3] = (f16)C[3];
        *(unsigned long long*)(hh + (size_t)(n0 + nl) * HC + ct * 16 + q * 4) = pk.u;

        // att-score partials (av aligns exactly with C[0..3])
        sAcc = fmaf(C[0], av.x, sAcc); sAcc = fmaf(C[1], av.y, sAcc);
        sAcc = fmaf(C[2], av.z, sAcc); sAcc = fmaf(C[3], av.w, sAcc);
        dAcc = fmaf(C[0], dv.x, dAcc); dAcc = fmaf(C[1], dv.y, dAcc);
        dAcc = fmaf(C[2], dv.z, dAcc); dAcc = fmaf(C[3], dv.w, dAcc);

        if ((ct & 3) == 3) {            // head boundary: reduce over quads
            float s = sAcc; s += __shfl_xor(s, 16); s += __shfl_xor(s, 32);
            float d = dAcc; d += __shfl_xor(d, 16); d += __shfl_xor(d, 32);
            if (lane < 16) {
                a_src[(n0 + lane) * 4 + (ct >> 2)] = s;
                a_dst[(n0 + lane) * 4 + (ct >> 2)] = d;
            }
            sAcc = 0.f; dAcc = 0.f;
        }
    }
}

// ---------------- K2: single-pass GAT aggregation (one wave per node) -------
// R2's verified 12-outstanding gather loop (R8's 24-deep arrays pushed VGPRs
// past the 64 cap at 8 blocks/CU -> regression). Delta vs R2: out_pre stored
// as f16 (stats still computed fp32 pre-rounding; error ~4e-3 << 0.133 thr).
__global__ __launch_bounds__(256, 8) void k_node(
        const f16* __restrict__ hh,
        const float* __restrict__ a_src,  // [N][4]
        const float* __restrict__ a_dst,  // [N][4]
        const int* __restrict__ cnt,
        const unsigned short* __restrict__ csr_pad,
        const float* __restrict__ bias,
        f16* __restrict__ out_pre,
        float* __restrict__ gp1,
        float* __restrict__ gp2) {
    const int lane = threadIdx.x & 63;
    const int wv = threadIdx.x >> 6;
    const int n = blockIdx.x * 4 + wv;

    int deg = cnt[n]; if (deg > PAD) deg = PAD;
    const unsigned short* __restrict__ row = csr_pad + n * PAD;

    const float ad0 = a_dst[n * 4 + 0], ad1 = a_dst[n * 4 + 1], ad2 = a_dst[n * 4 + 2];

    // self loop
    float ws0 = __expf(lrelu(a_src[n * 4 + 0] + ad0));
    float ws1 = __expf(lrelu(a_src[n * 4 + 1] + ad1));
    float ws2 = __expf(lrelu(a_src[n * 4 + 2] + ad2));
    float den0 = ws0, den1 = ws1, den2 = ws2;
    const f16* hn = hh + (size_t)n * HC;
    float acc0 = ws0 * (float)hn[lane];
    float acc1 = ws1 * (float)hn[64 + lane];
    float acc2 = ws2 * (float)hn[128 + lane];

    // deg <= PAD = 64 -> single chunk
    int s = 0;
    float w0 = 0.f, w1 = 0.f, w2 = 0.f;
    if (lane < deg) {
        s = (int)row[lane];
        float4 as = ((const float4*)a_src)[s];   // L2-resident (512 KB)
        w0 = __expf(lrelu(as.x + ad0));
        w1 = __expf(lrelu(as.y + ad1));
        w2 = __expf(lrelu(as.z + ad2));
    }
    den0 += wave_sum(w0);
    den1 += wave_sum(w1);
    den2 += wave_sum(w2);

    int j = 0;
    for (; j + 8 <= deg; j += 8) {      // 12 outstanding gathers per 4-group
#pragma unroll
        for (int u = 0; u < 8; u += 4) {
            int s0 = __builtin_amdgcn_readlane(s, j + u);
            int s1 = __builtin_amdgcn_readlane(s, j + u + 1);
            int s2 = __builtin_amdgcn_readlane(s, j + u + 2);
            int s3 = __builtin_amdgcn_readlane(s, j + u + 3);
            const f16* __restrict__ h0 = hh + (size_t)s0 * HC;
            const f16* __restrict__ h1 = hh + (size_t)s1 * HC;
            const f16* __restrict__ h2 = hh + (size_t)s2 * HC;
            const f16* __restrict__ h3 = hh + (size_t)s3 * HC;
            float v00 = (float)h0[lane], v01 = (float)h0[64 + lane], v02 = (float)h0[128 + lane];
            float v10 = (float)h1[lane], v11 = (float)h1[64 + lane], v12 = (float)h1[128 + lane];
            float v20 = (float)h2[lane], v21 = (float)h2[64 + lane], v22 = (float)h2[128 + lane];
            float v30 = (float)h3[lane], v31 = (float)h3[64 + lane], v32 = (float)h3[128 + lane];
            float w00 = rlane(w0, j + u),     w01 = rlane(w1, j + u),     w02 = rlane(w2, j + u);
            float w10 = rlane(w0, j + u + 1), w11 = rlane(w1, j + u + 1), w12 = rlane(w2, j + u + 1);
            float w20 = rlane(w0, j + u + 2), w21 = rlane(w1, j + u + 2), w22 = rlane(w2, j + u + 2);
            float w30 = rlane(w0, j + u + 3), w31 = rlane(w1, j + u + 3), w32 = rlane(w2, j + u + 3);
            acc0 = fmaf(w00, v00, acc0); acc0 = fmaf(w10, v10, acc0);
            acc0 = fmaf(w20, v20, acc0); acc0 = fmaf(w30, v30, acc0);
            acc1 = fmaf(w01, v01, acc1); acc1 = fmaf(w11, v11, acc1);
            acc1 = fmaf(w21, v21, acc1); acc1 = fmaf(w31, v31, acc1);
            acc2 = fmaf(w02, v02, acc2); acc2 = fmaf(w12, v12, acc2);
            acc2 = fmaf(w22, v22, acc2); acc2 = fmaf(w32, v32, acc2);
        }
    }
    for (; j < deg; j++) {
        int sa = __builtin_amdgcn_readlane(s, j);
        const f16* __restrict__ ha = hh + (size_t)sa * HC;
        float wa0 = rlane(w0, j), wa1 = rlane(w1, j), wa2 = rlane(w2, j);
        acc0 = fmaf(wa0, (float)ha[lane], acc0);
        acc1 = fmaf(wa1, (float)ha[64 + lane], acc1);
        acc2 = fmaf(wa2, (float)ha[128 + lane], acc2);
    }

    float outv = (acc0 / den0 + acc1 / den1 + acc2 / den2) * (1.0f / 3.0f) + bias[lane];
    out_pre[(size_t)n * 64 + lane] = (f16)outv;

    // fused BN partial stats (fp32, pre-rounding)
    __shared__ float ls[4][64], lq[4][64];
    ls[wv][lane] = outv;
    lq[wv][lane] = outv * outv;
    __syncthreads();
    if (threadIdx.x < 64) {
        int t = threadIdx.x;
        float s_ = ls[0][t] + ls[1][t] + ls[2][t] + ls[3][t];
        float q_ = lq[0][t] + lq[1][t] + lq[2][t] + lq[3][t];
        int slice = blockIdx.x & 63;
        atomicAdd(&gp1[slice * 64 + t], s_);
        atomicAdd(&gp2[slice * 64 + t], q_);
    }
}

// ---------------- K3: BN finalize (parallel over 256 thr) + apply -----------
__global__ __launch_bounds__(256) void k_apply(const f16* __restrict__ out_pre,
                                               const float* __restrict__ gp1,
                                               const float* __restrict__ gp2,
                                               const float* __restrict__ gamma,
                                               const float* __restrict__ beta,
                                               float4* __restrict__ out4) {
    __shared__ float sc[64], sh[64];
    __shared__ float rs[256], rq[256];
    {
        const int t = threadIdx.x & 63, g = threadIdx.x >> 6;
        float s = 0.f, q = 0.f;
#pragma unroll
        for (int i = 0; i < 16; i++) {
            s += gp1[(g * 16 + i) * 64 + t];
            q += gp2[(g * 16 + i) * 64 + t];
        }
        rs[threadIdx.x] = s;
        rq[threadIdx.x] = q;
    }
    __syncthreads();
    if (threadIdx.x < 64) {
        int t = threadIdx.x;
        float s = rs[t] + rs[64 + t] + rs[128 + t] + rs[192 + t];
        float q = rq[t] + rq[64 + t] + rq[128 + t] + rq[192 + t];
        const float inv_n = 1.0f / (float)N_NODES;
        float mu = s * inv_n;
        float var = q * inv_n - mu * mu;
        float invstd = 1.0f / sqrtf(var + BN_EPS);
        float scale = invstd * gamma[t];
        sc[t] = scale;
        sh[t] = beta[t] - mu * scale;
    }
    __syncthreads();
    const int total = N_NODES * 64 / 8;           // chunks of 8 f16
    for (int idx = blockIdx.x * 256 + threadIdx.x; idx < total; idx += APPLY_BLOCKS * 256) {
        const int c0 = (idx * 8) & 63;
        v8h v = *(const v8h*)(out_pre + (size_t)idx * 8);
        float4 r0, r1;
        r0.x = fmaxf((float)v[0] * sc[c0 + 0] + sh[c0 + 0], 0.f);
        r0.y = fmaxf((float)v[1] * sc[c0 + 1] + sh[c0 + 1], 0.f);
        r0.z = fmaxf((float)v[2] * sc[c0 + 2] + sh[c0 + 2], 0.f);
        r0.w = fmaxf((float)v[3] * sc[c0 + 3] + sh[c0 + 3], 0.f);
        r1.x = fmaxf((float)v[4] * sc[c0 + 4] + sh[c0 + 4], 0.f);
        r1.y = fmaxf((float)v[5] * sc[c0 + 5] + sh[c0 + 5], 0.f);
        r1.z = fmaxf((float)v[6] * sc[c0 + 6] + sh[c0 + 6], 0.f);
        r1.w = fmaxf((float)v[7] * sc[c0 + 7] + sh[c0 + 7], 0.f);
        out4[idx * 2]     = r0;
        out4[idx * 2 + 1] = r1;
    }
}

// ---------------- host launcher ----------------------------------------------
extern "C" void kernel_launch(void* const* d_in, const int* in_sizes, int n_in,
                              void* d_out, int out_size, void* d_ws, size_t ws_size,
                              hipStream_t stream) {
    const float* x     = (const float*)d_in[0];
    const int*   ei    = (const int*)d_in[2];     // [2, E]: row0 src, row1 dst
    const float* W     = (const float*)d_in[3];
    const float* att_s = (const float*)d_in[4];
    const float* att_d = (const float*)d_in[5];
    const float* bias  = (const float*)d_in[6];
    const float* gamma = (const float*)d_in[9];
    const float* beta  = (const float*)d_in[10];
    float* out = (float*)d_out;

    char* ws = (char*)d_ws;
    size_t off = 0;
    auto alloc = [&](size_t bytes) -> void* {
        void* p = ws + off;
        off += (bytes + 255) & ~(size_t)255;
        return p;
    };
    f16*            hh      = (f16*)alloc((size_t)N_NODES * HC * 2);       // 12.6 MB
    float*          a_src   = (float*)alloc((size_t)N_NODES * 4 * 4);      // 512 KB
    float*          a_dst   = (float*)alloc((size_t)N_NODES * 4 * 4);
    int*            cnt     = (int*)alloc((size_t)N_NODES * 4);            // 128 KB
    unsigned short* csr_pad = (unsigned short*)alloc((size_t)N_NODES * PAD * 2); // 4 MB
    f16*            out_pre = (f16*)alloc((size_t)N_NODES * 64 * 2);       // 4.2 MB
    float*          gp1     = (float*)alloc(64 * 64 * 4);
    float*          gp2     = (float*)alloc(64 * 64 * 4);

    hipMemsetAsync(cnt, 0, (size_t)N_NODES * 4, stream);

    k_fused<<<FUSED_BLOCKS, 256, 0, stream>>>(
        ei, ei + E_EDGES, cnt, csr_pad,
        x, W, att_s, att_d, hh, a_src, a_dst, gp1, gp2);
    k_node<<<NODE_BLOCKS, 256, 0, stream>>>(hh, a_src, a_dst, cnt, csr_pad, bias,
                                            out_pre, gp1, gp2);
    k_apply<<<APPLY_BLOCKS, 256, 0, stream>>>(out_pre, gp1, gp2,
                                              gamma, beta, (float4*)out);
}